// Round 7
// baseline (180.850 us; speedup 1.0000x reference)
//
#include <hip/hip_runtime.h>
#include <hip/hip_bf16.h>
#include <hip/hip_fp16.h>

// B=16, S=100, D=8192, P=100, W=3
constexpr int Dk   = 8192;
constexpr int Bb   = 16;
constexpr int Ss   = 100;
constexpr int Pp   = 100;
constexpr int MROW = 1632;     // 16 * 102 padded rows
constexpr int NT   = 20;       // n-tiles of 16 -> 320 cols (q|k|v|20 zero)
constexpr int NCC  = 320;
constexpr int KG   = 1024;     // k-groups of 8 (K=8192)
constexpr int KC   = 32;       // K splits (chunk 256)
constexpr int CH   = 5;        // attn positions per block
constexpr int MB   = 26;       // m-blocks of 64 rows

constexpr size_t B_SEG   = (size_t)NT * KG * 128;   // shorts per B segment
constexpr size_t PSTRIDE = (size_t)1664 * NCC;      // halfs per part slice

typedef short s8v __attribute__((ext_vector_type(8)));
typedef float f4v __attribute__((ext_vector_type(4)));

__device__ inline unsigned short f2bf_rne(float f) {
    unsigned u = __float_as_uint(f);
    u += 0x7fffu + ((u >> 16) & 1u);
    return (unsigned short)(u >> 16);
}

// Pack [wq|wk|wv|0] into hi/lo fragment layout [nt][kg][lane16][8].
__global__ __launch_bounds__(256) void pack_b(
    const float* __restrict__ wq, const float* __restrict__ wk,
    const float* __restrict__ wv,
    short* __restrict__ b_hi, short* __restrict__ b_lo) {
    const int id = blockIdx.x * 256 + threadIdx.x;
    const int n  = id % NCC;
    const int kg = id / NCC;
    if (kg >= KG) return;

    const float* w = nullptr; int p = 0;
    if (n < 100)      { w = wq; p = n; }
    else if (n < 200) { w = wk; p = n - 100; }
    else if (n < 300) { w = wv; p = n - 200; }

    s8v hi, lo;
    #pragma unroll
    for (int j = 0; j < 8; ++j) {
        const float v = w ? w[(size_t)(kg * 8 + j) * Pp + p] : 0.0f;
        const unsigned u = __float_as_uint(v);
        hi[j] = (short)(unsigned short)(u >> 16);                 // trunc split
        const float hf = __uint_as_float(u & 0xffff0000u);
        lo[j] = (short)f2bf_rne(v - hf);
    }
    const size_t doff = ((size_t)(n >> 4) * KG + kg) * 128 + (size_t)(n & 15) * 8;
    *(s8v*)(b_hi + doff) = hi;
    *(s8v*)(b_lo + doff) = lo;
}

// Barrier-free fused QKV GEMM. Grid (26 mb, 32 kc); 256 thr = 4 n-waves.
// Block/wave tile 64(M) x 80-per-wave(N): 4 m-frags x 5 n-frags, 60 MFMA/step.
// A loaded fp32 per-lane in frag layout (SSA double-buffered), converted
// in-register to hi/lo bf16. B from L2-hot packed buffers, loaded at use.
// fp16 partials, row-major [kc][row][col].
__global__ __launch_bounds__(256) void qkv_gemm(
    const float* __restrict__ x, const float* __restrict__ fpad,
    const float* __restrict__ bpad,
    const short* __restrict__ b_hi, const short* __restrict__ b_lo,
    unsigned short* __restrict__ part) {
    const int mb   = blockIdx.x;         // 0..25
    const int kc   = blockIdx.y;         // 0..31
    const int tid  = threadIdx.x;
    const int w    = tid >> 6;           // nw 0..3
    const int l    = tid & 63;
    const int m    = l & 15;
    const int quad = l >> 4;

    // per-lane A fragment pointers: row = mb*64 + i*16 + m, k base = kc*256 + quad*8
    const float* ap[4];
    #pragma unroll
    for (int i = 0; i < 4; ++i) {
        const int r = mb * 64 + i * 16 + m;
        const float* src;
        if (r >= MROW) src = fpad;       // junk rows, never read downstream
        else {
            const int b = r / 102, rr = r - b * 102;
            if (rr == 0)        src = fpad + (size_t)b * Dk;
            else if (rr == 101) src = bpad + (size_t)b * Dk;
            else                src = x + ((size_t)b * Ss + (rr - 1)) * Dk;
        }
        ap[i] = src + kc * 256 + quad * 8;
    }

    const int nt0 = w * 5;

    f4v acc[4][5];
    #pragma unroll
    for (int i = 0; i < 4; ++i)
        #pragma unroll
        for (int j = 0; j < 5; ++j) {
            f4v z = {0.f, 0.f, 0.f, 0.f};
            acc[i][j] = z;
        }

    // SSA double-buffered A
    float4 aA[4][2], aB[4][2];

    #pragma unroll
    for (int i = 0; i < 4; ++i) {
        aA[i][0] = *(const float4*)(ap[i]);
        aA[i][1] = *(const float4*)(ap[i] + 4);
    }

    #pragma unroll
    for (int s = 0; s < 8; ++s) {
        // prefetch next step's A into the other buffer
        if (s < 7) {
            if ((s & 1) == 0) {
                #pragma unroll
                for (int i = 0; i < 4; ++i) {
                    aB[i][0] = *(const float4*)(ap[i] + (s + 1) * 32);
                    aB[i][1] = *(const float4*)(ap[i] + (s + 1) * 32 + 4);
                }
            } else {
                #pragma unroll
                for (int i = 0; i < 4; ++i) {
                    aA[i][0] = *(const float4*)(ap[i] + (s + 1) * 32);
                    aA[i][1] = *(const float4*)(ap[i] + (s + 1) * 32 + 4);
                }
            }
        }

        // convert current A to hi/lo bf16
        s8v ah[4], al[4];
        #pragma unroll
        for (int i = 0; i < 4; ++i) {
            const float4 v0 = ((s & 1) == 0) ? aA[i][0] : aB[i][0];
            const float4 v1 = ((s & 1) == 0) ? aA[i][1] : aB[i][1];
            const float vv[8] = {v0.x, v0.y, v0.z, v0.w, v1.x, v1.y, v1.z, v1.w};
            #pragma unroll
            for (int jj = 0; jj < 8; ++jj) {
                const unsigned u = __float_as_uint(vv[jj]);
                ah[i][jj] = (short)(unsigned short)(u >> 16);
                al[i][jj] = (short)f2bf_rne(vv[jj] - __uint_as_float(u & 0xffff0000u));
            }
        }

        // B at use (L2-hot), 60 MFMAs
        const int kg = kc * 32 + s * 4 + quad;
        #pragma unroll
        for (int j = 0; j < 5; ++j) {
            const size_t bo = ((size_t)(nt0 + j) * KG + kg) * 128 + (size_t)m * 8;
            const s8v bh = *(const s8v*)(b_hi + bo);
            const s8v bl = *(const s8v*)(b_lo + bo);
            #pragma unroll
            for (int i = 0; i < 4; ++i)
                acc[i][j] = __builtin_amdgcn_mfma_f32_16x16x32_bf16(ah[i], bh, acc[i][j], 0, 0, 0);
            #pragma unroll
            for (int i = 0; i < 4; ++i)
                acc[i][j] = __builtin_amdgcn_mfma_f32_16x16x32_bf16(al[i], bh, acc[i][j], 0, 0, 0);
            #pragma unroll
            for (int i = 0; i < 4; ++i)
                acc[i][j] = __builtin_amdgcn_mfma_f32_16x16x32_bf16(ah[i], bl, acc[i][j], 0, 0, 0);
        }
    }

    // store fp16 partials, row-major [row][col]
    unsigned short* __restrict__ pout = part + (size_t)kc * PSTRIDE;
    #pragma unroll
    for (int i = 0; i < 4; ++i) {
        #pragma unroll
        for (int j = 0; j < 5; ++j) {
            const int col  = (nt0 + j) * 16 + m;
            const int row0 = mb * 64 + i * 16 + quad * 4;
            #pragma unroll
            for (int r = 0; r < 4; ++r)
                pout[(size_t)(row0 + r) * NCC + col] =
                    __half_as_ushort(__float2half(acc[i][j][r]));
        }
    }
}

// Fused k-split reduce + attention. Block = (b, chunk of 5 positions); grid 320.
__global__ __launch_bounds__(256) void reduce_attn(
    const unsigned short* __restrict__ part, float* __restrict__ out) {
    const int blk = blockIdx.x;          // 0..319
    const int b  = blk / (Ss / CH);
    const int c  = blk % (Ss / CH);
    const int s0 = c * CH;
    const int tid = threadIdx.x;

    __shared__ float red[CH + 2][304];   // rows s0..s0+6, cols 0..299
    __shared__ float sc[CH][3];

    // reduce 32 fp16 partial slices into LDS (coalesced 600B runs per (kc,row))
    for (int idx = tid; idx < (CH + 2) * 300; idx += 256) {
        const int row = idx / 300, col = idx % 300;
        const size_t base = (size_t)(b * 102 + s0 + row) * NCC + col;
        float sum = 0.0f;
        #pragma unroll
        for (int k = 0; k < KC; ++k)
            sum += __half2float(__ushort_as_half(part[(size_t)k * PSTRIDE + base]));
        red[row][col] = sum;
    }
    __syncthreads();

    // 15 score dots, one per 16-lane group: (ss,u): Q[ss+1].K[ss+u]
    if (tid < CH * 3 * 16) {
        const int d = tid >> 4, g = tid & 15;
        const int ss = d / 3, u = d % 3;
        float ps = 0.0f;
        #pragma unroll
        for (int t = 0; t < 7; ++t) {
            const int p = g + t * 16;
            if (p < Pp) ps += red[ss + 1][p] * red[ss + u][100 + p];
        }
        #pragma unroll
        for (int off = 8; off > 0; off >>= 1) ps += __shfl_down(ps, off, 16);
        if (g == 0) sc[ss][u] = ps;
    }
    __syncthreads();

    // outputs: softmax over 3, weighted V sum
    for (int idx = tid; idx < CH * Pp; idx += 256) {
        const int ss = idx / Pp, p = idx % Pp;
        const float a0 = sc[ss][0], a1 = sc[ss][1], a2 = sc[ss][2];
        const float mx = fmaxf(a0, fmaxf(a1, a2));
        const float e0 = __expf(a0 - mx), e1 = __expf(a1 - mx), e2 = __expf(a2 - mx);
        const float inv = 1.0f / (e0 + e1 + e2);
        out[(size_t)(b * Ss + s0 + ss) * Pp + p] =
            inv * (e0 * red[ss][200 + p] + e1 * red[ss + 1][200 + p] +
                   e2 * red[ss + 2][200 + p]);
    }
}

extern "C" void kernel_launch(void* const* d_in, const int* in_sizes, int n_in,
                              void* d_out, int out_size, void* d_ws, size_t ws_size,
                              hipStream_t stream) {
    const float* x    = (const float*)d_in[0];
    const float* wq   = (const float*)d_in[1];
    const float* wk   = (const float*)d_in[2];
    const float* wv   = (const float*)d_in[3];
    const float* fpad = (const float*)d_in[4];
    const float* bpad = (const float*)d_in[5];
    float* out = (float*)d_out;

    short* b_hi = (short*)d_ws;                              // 5.24 MB
    short* b_lo = b_hi + B_SEG;                              // 5.24 MB
    unsigned short* part = (unsigned short*)(b_lo + B_SEG);  // 32*1664*320 fp16 = 34.1 MB
    // total ws ~44.6 MB; part fully overwritten, no zeroing needed

    pack_b<<<(NCC * KG) / 256, 256, 0, stream>>>(wq, wk, wv, b_hi, b_lo);
    qkv_gemm<<<dim3(MB, KC), 256, 0, stream>>>(x, fpad, bpad, b_hi, b_lo, part);
    reduce_attn<<<Bb * (Ss / CH), 256, 0, stream>>>(part, out);
}

// Round 8
// 177.563 us; speedup vs baseline: 1.0185x; 1.0185x over previous
//
#include <hip/hip_runtime.h>
#include <hip/hip_bf16.h>
#include <hip/hip_fp16.h>

// B=16, S=100, D=8192, P=100, W=3
constexpr int Dk   = 8192;
constexpr int Bb   = 16;
constexpr int Ss   = 100;
constexpr int Pp   = 100;
constexpr int MROW = 1632;     // 16 * 102 padded rows
constexpr int NT   = 20;       // n-tiles of 16 -> 320 cols (q|k|v|20 zero)
constexpr int NCC  = 320;
constexpr int KG   = 1024;     // k-groups of 8 (K=8192)
constexpr int KC   = 32;       // K splits (chunk 256 = 8 steps of 32)
constexpr int CH   = 5;        // attn positions per block
constexpr int MBL  = 52;       // m-blocks of 32 rows

constexpr size_t B_SEG   = (size_t)NT * KG * 128;   // shorts per B segment
constexpr size_t PSTRIDE = (size_t)1664 * NCC;      // halfs per part slice

typedef short s8v __attribute__((ext_vector_type(8)));
typedef short s4v __attribute__((ext_vector_type(4)));
typedef float f4v __attribute__((ext_vector_type(4)));

__device__ inline unsigned short f2bf_rne(float f) {
    unsigned u = __float_as_uint(f);
    u += 0x7fffu + ((u >> 16) & 1u);
    return (unsigned short)(u >> 16);
}

// Pack [wq|wk|wv|0] into hi/lo fragment layout [nt][kg][lane16][8].
__global__ __launch_bounds__(256) void pack_b(
    const float* __restrict__ wq, const float* __restrict__ wk,
    const float* __restrict__ wv,
    short* __restrict__ b_hi, short* __restrict__ b_lo) {
    const int id = blockIdx.x * 256 + threadIdx.x;
    const int n  = id % NCC;
    const int kg = id / NCC;
    if (kg >= KG) return;

    const float* w = nullptr; int p = 0;
    if (n < 100)      { w = wq; p = n; }
    else if (n < 200) { w = wk; p = n - 100; }
    else if (n < 300) { w = wv; p = n - 200; }

    s8v hi, lo;
    #pragma unroll
    for (int j = 0; j < 8; ++j) {
        const float v = w ? w[(size_t)(kg * 8 + j) * Pp + p] : 0.0f;
        const unsigned u = __float_as_uint(v);
        hi[j] = (short)(unsigned short)(u >> 16);                 // trunc split
        const float hf = __uint_as_float(u & 0xffff0000u);
        lo[j] = (short)f2bf_rne(v - hf);
    }
    const size_t doff = ((size_t)(n >> 4) * KG + kg) * 128 + (size_t)(n & 15) * 8;
    *(s8v*)(b_hi + doff) = hi;
    *(s8v*)(b_lo + doff) = lo;
}

// Fused QKV GEMM. Grid (52 mb, 32 kc); 256 thr = 4 n-waves.
// Block tile 32(M) x 320(N); wave tile 32x80 (2 m-frags x 5 n-frags).
// All 8 steps of A loaded upfront (max lookahead); convert-once LDS staging
// with double-buffered LDS and ONE barrier per step. fp16 partials.
__global__ __launch_bounds__(256, 4) void qkv_gemm(
    const float* __restrict__ x, const float* __restrict__ fpad,
    const float* __restrict__ bpad,
    const short* __restrict__ b_hi, const short* __restrict__ b_lo,
    unsigned short* __restrict__ part) {
    __shared__ __align__(16) short ahis[2][1024];   // [buf][frag2][kg4][lane16][8]
    __shared__ __align__(16) short alos[2][1024];

    const int mb   = blockIdx.x;         // 0..51
    const int kc   = blockIdx.y;         // 0..31
    const int tid  = threadIdx.x;
    const int w    = tid >> 6;           // nw 0..3
    const int l    = tid & 63;
    const int m    = l & 15;
    const int quad = l >> 4;

    // staging role: thread -> (row sr, k-offset skq*4)
    const int sr  = tid >> 3;            // 0..31
    const int skq = tid & 7;             // 0..7
    const float* sp;
    {
        const int r = mb * 32 + sr;
        if (r >= MROW) sp = fpad;        // junk rows, never read downstream
        else {
            const int b = r / 102, rr = r - b * 102;
            if (rr == 0)        sp = fpad + (size_t)b * Dk;
            else if (rr == 101) sp = bpad + (size_t)b * Dk;
            else                sp = x + ((size_t)b * Ss + (rr - 1)) * Dk;
        }
        sp += kc * 256 + skq * 4;
    }
    const int woff = ((sr >> 4) * 4 + (skq >> 1)) * 128 + (sr & 15) * 8 + (skq & 1) * 4;

    // ---- issue ALL 8 A-step loads upfront (independent, stay in flight) ----
    float4 av[8];
    #pragma unroll
    for (int s = 0; s < 8; ++s) av[s] = *(const float4*)(sp + s * 32);

    f4v acc[2][5];
    #pragma unroll
    for (int i = 0; i < 2; ++i)
        #pragma unroll
        for (int j = 0; j < 5; ++j) {
            f4v z = {0.f, 0.f, 0.f, 0.f};
            acc[i][j] = z;
        }

    #pragma unroll
    for (int s = 0; s < 8; ++s) {
        const int buf = s & 1;
        // convert this step's A to hi/lo bf16
        const float vv[4] = {av[s].x, av[s].y, av[s].z, av[s].w};
        s4v h4, l4;
        #pragma unroll
        for (int jj = 0; jj < 4; ++jj) {
            const unsigned u = __float_as_uint(vv[jj]);
            h4[jj] = (short)(unsigned short)(u >> 16);
            l4[jj] = (short)f2bf_rne(vv[jj] - __uint_as_float(u & 0xffff0000u));
        }
        *(s4v*)&ahis[buf][woff] = h4;
        *(s4v*)&alos[buf][woff] = l4;
        __syncthreads();   // publish buf; prev buf's reads were consumed pre-arrival

        // A fragments from LDS
        const s8v ah0 = *(const s8v*)&ahis[buf][(quad * 16 + m) * 8];
        const s8v ah1 = *(const s8v*)&ahis[buf][((4 + quad) * 16 + m) * 8];
        const s8v al0 = *(const s8v*)&alos[buf][(quad * 16 + m) * 8];
        const s8v al1 = *(const s8v*)&alos[buf][((4 + quad) * 16 + m) * 8];

        // B at use (L2-hot), 30 MFMAs
        const int kg = kc * 32 + s * 4 + quad;
        #pragma unroll
        for (int j = 0; j < 5; ++j) {
            const size_t bo = ((size_t)(w * 5 + j) * KG + kg) * 128 + (size_t)m * 8;
            const s8v bh = *(const s8v*)(b_hi + bo);
            const s8v bl = *(const s8v*)(b_lo + bo);
            acc[0][j] = __builtin_amdgcn_mfma_f32_16x16x32_bf16(ah0, bh, acc[0][j], 0, 0, 0);
            acc[1][j] = __builtin_amdgcn_mfma_f32_16x16x32_bf16(ah1, bh, acc[1][j], 0, 0, 0);
            acc[0][j] = __builtin_amdgcn_mfma_f32_16x16x32_bf16(al0, bh, acc[0][j], 0, 0, 0);
            acc[1][j] = __builtin_amdgcn_mfma_f32_16x16x32_bf16(al1, bh, acc[1][j], 0, 0, 0);
            acc[0][j] = __builtin_amdgcn_mfma_f32_16x16x32_bf16(ah0, bl, acc[0][j], 0, 0, 0);
            acc[1][j] = __builtin_amdgcn_mfma_f32_16x16x32_bf16(ah1, bl, acc[1][j], 0, 0, 0);
        }
    }

    // store fp16 partials, row-major [kc][row][col]
    unsigned short* __restrict__ pout = part + (size_t)kc * PSTRIDE;
    #pragma unroll
    for (int i = 0; i < 2; ++i) {
        #pragma unroll
        for (int j = 0; j < 5; ++j) {
            const int col  = (w * 5 + j) * 16 + m;
            const int row0 = mb * 32 + i * 16 + quad * 4;
            #pragma unroll
            for (int r = 0; r < 4; ++r)
                pout[(size_t)(row0 + r) * NCC + col] =
                    __half_as_ushort(__float2half(acc[i][j][r]));
        }
    }
}

// Fused k-split reduce + attention. Block = (b, chunk of 5 positions); grid 320.
__global__ __launch_bounds__(256) void reduce_attn(
    const unsigned short* __restrict__ part, float* __restrict__ out) {
    const int blk = blockIdx.x;          // 0..319
    const int b  = blk / (Ss / CH);
    const int c  = blk % (Ss / CH);
    const int s0 = c * CH;
    const int tid = threadIdx.x;

    __shared__ float red[CH + 2][304];   // rows s0..s0+6, cols 0..299
    __shared__ float sc[CH][3];

    // reduce 32 fp16 partial slices into LDS; ushort4 (8B) coalesced loads
    for (int idx = tid; idx < (CH + 2) * 75; idx += 256) {
        const int row = idx / 75, cg = idx % 75;
        const size_t base = ((size_t)(b * 102 + s0 + row) * NCC + cg * 4) >> 2;
        float s0v = 0.f, s1v = 0.f, s2v = 0.f, s3v = 0.f;
        #pragma unroll
        for (int k = 0; k < KC; ++k) {
            const ushort4 u = ((const ushort4*)part)[(size_t)k * (PSTRIDE >> 2) + base];
            s0v += __half2float(__ushort_as_half(u.x));
            s1v += __half2float(__ushort_as_half(u.y));
            s2v += __half2float(__ushort_as_half(u.z));
            s3v += __half2float(__ushort_as_half(u.w));
        }
        red[row][cg * 4 + 0] = s0v;
        red[row][cg * 4 + 1] = s1v;
        red[row][cg * 4 + 2] = s2v;
        red[row][cg * 4 + 3] = s3v;
    }
    __syncthreads();

    // 15 score dots, one per 16-lane group: (ss,u): Q[ss+1].K[ss+u]
    if (tid < CH * 3 * 16) {
        const int d = tid >> 4, g = tid & 15;
        const int ss = d / 3, u = d % 3;
        float ps = 0.0f;
        #pragma unroll
        for (int t = 0; t < 7; ++t) {
            const int p = g + t * 16;
            if (p < Pp) ps += red[ss + 1][p] * red[ss + u][100 + p];
        }
        #pragma unroll
        for (int off = 8; off > 0; off >>= 1) ps += __shfl_down(ps, off, 16);
        if (g == 0) sc[ss][u] = ps;
    }
    __syncthreads();

    // outputs: softmax over 3, weighted V sum
    for (int idx = tid; idx < CH * Pp; idx += 256) {
        const int ss = idx / Pp, p = idx % Pp;
        const float a0 = sc[ss][0], a1 = sc[ss][1], a2 = sc[ss][2];
        const float mx = fmaxf(a0, fmaxf(a1, a2));
        const float e0 = __expf(a0 - mx), e1 = __expf(a1 - mx), e2 = __expf(a2 - mx);
        const float inv = 1.0f / (e0 + e1 + e2);
        out[(size_t)(b * Ss + s0 + ss) * Pp + p] =
            inv * (e0 * red[ss][200 + p] + e1 * red[ss + 1][200 + p] +
                   e2 * red[ss + 2][200 + p]);
    }
}

extern "C" void kernel_launch(void* const* d_in, const int* in_sizes, int n_in,
                              void* d_out, int out_size, void* d_ws, size_t ws_size,
                              hipStream_t stream) {
    const float* x    = (const float*)d_in[0];
    const float* wq   = (const float*)d_in[1];
    const float* wk   = (const float*)d_in[2];
    const float* wv   = (const float*)d_in[3];
    const float* fpad = (const float*)d_in[4];
    const float* bpad = (const float*)d_in[5];
    float* out = (float*)d_out;

    short* b_hi = (short*)d_ws;                              // 5.24 MB
    short* b_lo = b_hi + B_SEG;                              // 5.24 MB
    unsigned short* part = (unsigned short*)(b_lo + B_SEG);  // 32*1664*320 fp16 = 34.1 MB
    // total ws ~44.6 MB; part fully overwritten, no zeroing needed

    pack_b<<<(NCC * KG) / 256, 256, 0, stream>>>(wq, wk, wv, b_hi, b_lo);
    qkv_gemm<<<dim3(MBL, KC), 256, 0, stream>>>(x, fpad, bpad, b_hi, b_lo, part);
    reduce_attn<<<Bb * (Ss / CH), 256, 0, stream>>>(part, out);
}

// Round 9
// 141.531 us; speedup vs baseline: 1.2778x; 1.2546x over previous
//
#include <hip/hip_runtime.h>
#include <hip/hip_bf16.h>
#include <hip/hip_fp16.h>

// B=16, S=100, D=8192, P=100, W=3
constexpr int Dk   = 8192;
constexpr int Bb   = 16;
constexpr int Ss   = 100;
constexpr int Pp   = 100;
constexpr int MROW = 1632;     // 16 * 102 padded rows
constexpr int NT   = 20;       // n-tiles of 16 -> 320 cols (q|k|v|20 zero)
constexpr int NCC  = 320;
constexpr int NQ   = 304;      // reduced qkv row stride (fp32)
constexpr int KG   = 1024;     // k-groups of 8 (K=8192)
constexpr int KC   = 16;       // K splits (chunk 512 = 16 steps of 32)
constexpr int CH   = 5;        // attn positions per block
constexpr int MBL  = 52;       // m-blocks of 32 rows

constexpr size_t B_SEG   = (size_t)NT * KG * 128;   // shorts per B segment
constexpr size_t PSTRIDE = (size_t)1664 * NCC;      // halfs per part slice

typedef short s8v __attribute__((ext_vector_type(8)));
typedef short s4v __attribute__((ext_vector_type(4)));
typedef float f4v __attribute__((ext_vector_type(4)));

__device__ inline unsigned short f2bf_rne(float f) {
    unsigned u = __float_as_uint(f);
    u += 0x7fffu + ((u >> 16) & 1u);
    return (unsigned short)(u >> 16);
}

// Pack [wq|wk|wv|0] into hi/lo fragment layout [nt][kg][lane16][8].
__global__ __launch_bounds__(256) void pack_b(
    const float* __restrict__ wq, const float* __restrict__ wk,
    const float* __restrict__ wv,
    short* __restrict__ b_hi, short* __restrict__ b_lo) {
    const int id = blockIdx.x * 256 + threadIdx.x;
    const int n  = id % NCC;
    const int kg = id / NCC;
    if (kg >= KG) return;

    const float* w = nullptr; int p = 0;
    if (n < 100)      { w = wq; p = n; }
    else if (n < 200) { w = wk; p = n - 100; }
    else if (n < 300) { w = wv; p = n - 200; }

    s8v hi, lo;
    #pragma unroll
    for (int j = 0; j < 8; ++j) {
        const float v = w ? w[(size_t)(kg * 8 + j) * Pp + p] : 0.0f;
        const unsigned u = __float_as_uint(v);
        hi[j] = (short)(unsigned short)(u >> 16);                 // trunc split
        const float hf = __uint_as_float(u & 0xffff0000u);
        lo[j] = (short)f2bf_rne(v - hf);
    }
    const size_t doff = ((size_t)(n >> 4) * KG + kg) * 128 + (size_t)(n & 15) * 8;
    *(s8v*)(b_hi + doff) = hi;
    *(s8v*)(b_lo + doff) = lo;
}

// Fused QKV GEMM. Grid (52 mb, 16 kc); 256 thr = 4 n-waves.
// Block tile 32(M) x 320(N); wave tile 32x80 (2 m-frags x 5 n-frags).
// K-chunk 512 = 16 steps of 32. A: depth-4 register ring + convert-once LDS
// staging (double buffer, ONE barrier/step). B: register ping-pong prefetched
// one full step ahead, ISSUED BEFORE THE BARRIER (breaks per-step L2 chain).
__global__ __launch_bounds__(256, 2) void qkv_gemm(
    const float* __restrict__ x, const float* __restrict__ fpad,
    const float* __restrict__ bpad,
    const short* __restrict__ b_hi, const short* __restrict__ b_lo,
    unsigned short* __restrict__ part) {
    __shared__ __align__(16) short ahis[2][1024];   // [buf][frag2][kg4][lane16][8]
    __shared__ __align__(16) short alos[2][1024];

    const int mb   = blockIdx.x;         // 0..51
    const int kc   = blockIdx.y;         // 0..15
    const int tid  = threadIdx.x;
    const int w    = tid >> 6;           // nw 0..3
    const int l    = tid & 63;
    const int m    = l & 15;
    const int quad = l >> 4;

    // staging role: thread -> (row sr, k-offset skq*4)
    const int sr  = tid >> 3;            // 0..31
    const int skq = tid & 7;             // 0..7
    const float* sp;
    {
        const int r = mb * 32 + sr;
        if (r >= MROW) sp = fpad;        // junk rows, never read downstream
        else {
            const int b = r / 102, rr = r - b * 102;
            if (rr == 0)        sp = fpad + (size_t)b * Dk;
            else if (rr == 101) sp = bpad + (size_t)b * Dk;
            else                sp = x + ((size_t)b * Ss + (rr - 1)) * Dk;
        }
        sp += kc * 512 + skq * 4;
    }
    const int woff = ((sr >> 4) * 4 + (skq >> 1)) * 128 + (sr & 15) * 8 + (skq & 1) * 4;

    // ---- A register ring, depth 4 ----
    float4 av[4];
    #pragma unroll
    for (int p = 0; p < 4; ++p) av[p] = *(const float4*)(sp + p * 32);

    // ---- B register ping-pong, preload step 0 ----
    s8v bh[2][5], bl[2][5];
    {
        const int kg0 = kc * 64 + quad;
        #pragma unroll
        for (int j = 0; j < 5; ++j) {
            const size_t bo = ((size_t)(w * 5 + j) * KG + kg0) * 128 + (size_t)m * 8;
            bh[0][j] = *(const s8v*)(b_hi + bo);
            bl[0][j] = *(const s8v*)(b_lo + bo);
        }
    }

    f4v acc[2][5];
    #pragma unroll
    for (int i = 0; i < 2; ++i)
        #pragma unroll
        for (int j = 0; j < 5; ++j) {
            f4v z = {0.f, 0.f, 0.f, 0.f};
            acc[i][j] = z;
        }

    #pragma unroll
    for (int s = 0; s < 16; ++s) {
        const int cur = s & 1, nxt = cur ^ 1;

        // B prefetch for NEXT step, issued before this step's barrier
        if (s < 15) {
            const int kgn = kc * 64 + (s + 1) * 4 + quad;
            #pragma unroll
            for (int j = 0; j < 5; ++j) {
                const size_t bo = ((size_t)(w * 5 + j) * KG + kgn) * 128 + (size_t)m * 8;
                bh[nxt][j] = *(const s8v*)(b_hi + bo);
                bl[nxt][j] = *(const s8v*)(b_lo + bo);
            }
        }

        // convert this step's A (ring slot s&3) to hi/lo bf16
        const float4 va = av[s & 3];
        const float vv[4] = {va.x, va.y, va.z, va.w};
        s4v h4, l4;
        #pragma unroll
        for (int jj = 0; jj < 4; ++jj) {
            const unsigned u = __float_as_uint(vv[jj]);
            h4[jj] = (short)(unsigned short)(u >> 16);
            l4[jj] = (short)f2bf_rne(vv[jj] - __uint_as_float(u & 0xffff0000u));
        }
        // A prefetch 4 steps ahead into the freed slot
        if (s < 12) av[s & 3] = *(const float4*)(sp + (s + 4) * 32);

        *(s4v*)&ahis[cur][woff] = h4;
        *(s4v*)&alos[cur][woff] = l4;
        __syncthreads();   // publish buf; prior buf's reads consumed pre-arrival

        // A fragments from LDS
        const s8v ah0 = *(const s8v*)&ahis[cur][(quad * 16 + m) * 8];
        const s8v ah1 = *(const s8v*)&ahis[cur][((4 + quad) * 16 + m) * 8];
        const s8v al0 = *(const s8v*)&alos[cur][(quad * 16 + m) * 8];
        const s8v al1 = *(const s8v*)&alos[cur][((4 + quad) * 16 + m) * 8];

        // 30 MFMAs on register-resident B
        #pragma unroll
        for (int j = 0; j < 5; ++j) {
            const s8v bhv = bh[cur][j], blv = bl[cur][j];
            acc[0][j] = __builtin_amdgcn_mfma_f32_16x16x32_bf16(ah0, bhv, acc[0][j], 0, 0, 0);
            acc[1][j] = __builtin_amdgcn_mfma_f32_16x16x32_bf16(ah1, bhv, acc[1][j], 0, 0, 0);
            acc[0][j] = __builtin_amdgcn_mfma_f32_16x16x32_bf16(al0, bhv, acc[0][j], 0, 0, 0);
            acc[1][j] = __builtin_amdgcn_mfma_f32_16x16x32_bf16(al1, bhv, acc[1][j], 0, 0, 0);
            acc[0][j] = __builtin_amdgcn_mfma_f32_16x16x32_bf16(ah0, blv, acc[0][j], 0, 0, 0);
            acc[1][j] = __builtin_amdgcn_mfma_f32_16x16x32_bf16(ah1, blv, acc[1][j], 0, 0, 0);
        }
    }

    // store fp16 partials, row-major [kc][row][col]
    unsigned short* __restrict__ pout = part + (size_t)kc * PSTRIDE;
    #pragma unroll
    for (int i = 0; i < 2; ++i) {
        #pragma unroll
        for (int j = 0; j < 5; ++j) {
            const int col  = (w * 5 + j) * 16 + m;
            const int row0 = mb * 32 + i * 16 + quad * 4;
            #pragma unroll
            for (int r = 0; r < 4; ++r)
                pout[(size_t)(row0 + r) * NCC + col] =
                    __half_as_ushort(__float2half(acc[i][j][r]));
        }
    }
}

// Reduce KC fp16 partial slices -> fp32 qkv (stride 304).
// Grid 260 x 256; thread = (row, 8-col group): 16x 16B loads, 2x f32x4 stores.
__global__ __launch_bounds__(256) void reduce_k(
    const unsigned short* __restrict__ part, float* __restrict__ qkv) {
    const int t = blockIdx.x * 256 + threadIdx.x;   // 0..66559
    const int row = t / 40;
    const int col0 = (t - row * 40) * 8;
    const size_t base = (size_t)row * NCC + col0;

    float sum[8] = {0.f, 0.f, 0.f, 0.f, 0.f, 0.f, 0.f, 0.f};
    #pragma unroll
    for (int k = 0; k < KC; ++k) {
        const s8v u = *(const s8v*)(part + (size_t)k * PSTRIDE + base);
        #pragma unroll
        for (int ii = 0; ii < 8; ++ii)
            sum[ii] += __half2float(__ushort_as_half((unsigned short)u[ii]));
    }
    if (col0 < NQ) {
        f4v a = {sum[0], sum[1], sum[2], sum[3]};
        f4v b = {sum[4], sum[5], sum[6], sum[7]};
        *(f4v*)(qkv + (size_t)row * NQ + col0)     = a;
        *(f4v*)(qkv + (size_t)row * NQ + col0 + 4) = b;
    }
}

// Attention on reduced fp32 qkv. Block = (b, chunk of 5 positions); grid 320.
__global__ __launch_bounds__(256) void attn3(
    const float* __restrict__ qkv, float* __restrict__ out) {
    const int blk = blockIdx.x;          // 0..319
    const int b  = blk / (Ss / CH);
    const int c  = blk % (Ss / CH);
    const int s0 = c * CH;
    const int tid = threadIdx.x;

    __shared__ float red[CH + 2][304];   // rows s0..s0+6, cols 0..299
    __shared__ float sc[CH][3];

    for (int idx = tid; idx < (CH + 2) * 300; idx += 256) {
        const int row = idx / 300, col = idx % 300;
        red[row][col] = qkv[(size_t)(b * 102 + s0 + row) * NQ + col];
    }
    __syncthreads();

    // 15 score dots, one per 16-lane group: (ss,u): Q[ss+1].K[ss+u]
    if (tid < CH * 3 * 16) {
        const int d = tid >> 4, g = tid & 15;
        const int ss = d / 3, u = d % 3;
        float ps = 0.0f;
        #pragma unroll
        for (int t = 0; t < 7; ++t) {
            const int p = g + t * 16;
            if (p < Pp) ps += red[ss + 1][p] * red[ss + u][100 + p];
        }
        #pragma unroll
        for (int off = 8; off > 0; off >>= 1) ps += __shfl_down(ps, off, 16);
        if (g == 0) sc[ss][u] = ps;
    }
    __syncthreads();

    for (int idx = tid; idx < CH * Pp; idx += 256) {
        const int ss = idx / Pp, p = idx % Pp;
        const float a0 = sc[ss][0], a1 = sc[ss][1], a2 = sc[ss][2];
        const float mx = fmaxf(a0, fmaxf(a1, a2));
        const float e0 = __expf(a0 - mx), e1 = __expf(a1 - mx), e2 = __expf(a2 - mx);
        const float inv = 1.0f / (e0 + e1 + e2);
        out[(size_t)(b * Ss + s0 + ss) * Pp + p] =
            inv * (e0 * red[ss][200 + p] + e1 * red[ss + 1][200 + p] +
                   e2 * red[ss + 2][200 + p]);
    }
}

extern "C" void kernel_launch(void* const* d_in, const int* in_sizes, int n_in,
                              void* d_out, int out_size, void* d_ws, size_t ws_size,
                              hipStream_t stream) {
    const float* x    = (const float*)d_in[0];
    const float* wq   = (const float*)d_in[1];
    const float* wk   = (const float*)d_in[2];
    const float* wv   = (const float*)d_in[3];
    const float* fpad = (const float*)d_in[4];
    const float* bpad = (const float*)d_in[5];
    float* out = (float*)d_out;

    short* b_hi = (short*)d_ws;                              // 5.24 MB
    short* b_lo = b_hi + B_SEG;                              // 5.24 MB
    unsigned short* part = (unsigned short*)(b_lo + B_SEG);  // 16*1664*320 fp16 = 17.0 MB
    float* qkv = (float*)(part + (size_t)KC * PSTRIDE);      // 1664*304 fp32 = 2.0 MB
    // total ws ~29.6 MB; all buffers fully overwritten, no zeroing needed

    pack_b<<<(NCC * KG) / 256, 256, 0, stream>>>(wq, wk, wv, b_hi, b_lo);
    qkv_gemm<<<dim3(MBL, KC), 256, 0, stream>>>(x, fpad, bpad, b_hi, b_lo, part);
    reduce_k<<<260, 256, 0, stream>>>(part, qkv);
    attn3<<<Bb * (Ss / CH), 256, 0, stream>>>(qkv, out);
}